// Round 7
// baseline (325.349 us; speedup 1.0000x reference)
//
#include <hip/hip_runtime.h>
#include <math.h>

#define D 128
#define OUTD 64

typedef __attribute__((ext_vector_type(8))) short short8;
typedef __attribute__((ext_vector_type(4))) float floatx4;

static __device__ __forceinline__ float bf2f(unsigned short u) {
  return __uint_as_float(((unsigned int)u) << 16);
}
static __device__ __forceinline__ unsigned short f2bf(float f) {
  unsigned int u = __float_as_uint(f);
  u = (u + 0x7fff + ((u >> 16) & 1)) >> 16;   // RNE
  return (unsigned short)u;
}

// ---------------- CSR build + weight prep (merged dispatch) ----------------
// blocks [0, histB)          : deg histogram over dst
// blocks [histB, histB+192)  : Wt[l][n][k] = Ws[l][k][n] (bf16)
// blocks [histB+192, +224)   : Wct[j][k] = (Wp1 @ Wp2)[k][j] (bf16), bc

__global__ __launch_bounds__(256) void k_hist_prep(const int* __restrict__ ei,
                                                   int* __restrict__ deg, int E,
                                                   const float* __restrict__ Ws,
                                                   const float* __restrict__ Wp1,
                                                   const float* __restrict__ bp1,
                                                   const float* __restrict__ Wp2,
                                                   const float* __restrict__ bp2,
                                                   unsigned short* __restrict__ Wt,
                                                   unsigned short* __restrict__ Wct,
                                                   float* __restrict__ bc, int histB) {
  if (blockIdx.x < (unsigned)histB) {
    int e = blockIdx.x * 256 + threadIdx.x;
    if (e < E) atomicAdd(&deg[ei[E + e]], 1);
  } else if (blockIdx.x < (unsigned)histB + 192) {
    int gid = (blockIdx.x - histB) * 256 + threadIdx.x;   // 49152
    int l = gid >> 14;
    int rem = gid & 16383;
    int k = rem >> 7, n = rem & 127;
    Wt[l * 16384 + n * 128 + k] = f2bf(Ws[gid]);
  } else {
    int gid = (blockIdx.x - histB - 192) * 256 + threadIdx.x;   // 8192
    int i = gid >> 6, j = gid & 63;                             // i = k, j = col
    float acc = 0.f;
    for (int k = 0; k < 128; ++k) acc += Wp1[i * 128 + k] * Wp2[k * 64 + j];
    Wct[j * 128 + i] = f2bf(acc);
    if (gid < 64) {
      float b = bp2[gid];
      for (int k = 0; k < 128; ++k) b += bp1[k] * Wp2[k * 64 + gid];
      bc[gid] = b;
    }
  }
}

__global__ __launch_bounds__(1024) void k_scan1(const int* __restrict__ deg,
                                                int* __restrict__ offs,
                                                int* __restrict__ partial, int N) {
  __shared__ int wsum[16];
  int tid = threadIdx.x, lane = tid & 63, wv = tid >> 6;
  int i = blockIdx.x * 1024 + tid;
  int v = (i < N) ? deg[i] : 0;
  int x = v;
#pragma unroll
  for (int off = 1; off < 64; off <<= 1) {
    int t = __shfl_up(x, off);
    if (lane >= off) x += t;
  }
  if (lane == 63) wsum[wv] = x;
  __syncthreads();
  if (wv == 0) {
    int s = (lane < 16) ? wsum[lane] : 0;
#pragma unroll
    for (int off = 1; off < 16; off <<= 1) {
      int t = __shfl_up(s, off);
      if (lane >= off) s += t;
    }
    if (lane < 16) wsum[lane] = s;
  }
  __syncthreads();
  int wexcl = (wv == 0) ? 0 : wsum[wv - 1];
  if (i < N) offs[i] = wexcl + x - v;
  if (tid == 0) partial[blockIdx.x] = wsum[15];
}

__global__ __launch_bounds__(1024) void k_scan(const int* __restrict__ deg,
                                               int* __restrict__ offs, int N) {
  __shared__ int wsum[16];
  __shared__ int s_carry;
  int tid = threadIdx.x, lane = tid & 63, wv = tid >> 6;
  if (tid == 0) s_carry = 0;
  __syncthreads();
  for (int base = 0; base < N; base += 1024) {
    int i = base + tid;
    int v = (i < N) ? deg[i] : 0;
    int x = v;
#pragma unroll
    for (int off = 1; off < 64; off <<= 1) {
      int t = __shfl_up(x, off);
      if (lane >= off) x += t;
    }
    if (lane == 63) wsum[wv] = x;
    __syncthreads();
    if (wv == 0) {
      int s = (lane < 16) ? wsum[lane] : 0;
#pragma unroll
      for (int off = 1; off < 16; off <<= 1) {
        int t = __shfl_up(s, off);
        if (lane >= off) s += t;
      }
      if (lane < 16) wsum[lane] = s;
    }
    __syncthreads();
    int wexcl = (wv == 0) ? 0 : wsum[wv - 1];
    if (i < N) offs[i] = s_carry + wexcl + x - v;
    __syncthreads();
    if (tid == 1023) s_carry += wsum[15];
    __syncthreads();
  }
  if (tid == 0) offs[N] = s_carry;
}

__global__ __launch_bounds__(1024) void k_add(int* __restrict__ offs,
                                              const int* __restrict__ partialx, int N) {
  int i = blockIdx.x * 1024 + threadIdx.x;
  int a = partialx[blockIdx.x];
  if (i < N) offs[i] += a;
}

// atomicAdd directly on offs: afterwards offs[n] = END of node n's range.
__global__ void k_fill(const int* __restrict__ ei, int* __restrict__ offs,
                       int* __restrict__ csr_src, int E) {
  int e = blockIdx.x * 256 + threadIdx.x;
  if (e < E) {
    int d = ei[E + e];
    int pos = atomicAdd(&offs[d], 1);
    csr_src[pos] = ei[e];
  }
}

// ---------------- MFMA GEMM + fused attention scores ----------------
// H(bf16)[M x 128] = bf16(A) @ W + bias ; sdst/ssrc from f32 accumulators.
// SWAPPED mfma(fb, fa): thread holds H[row][cols g*4+{0..3}] -> ushort4 stores.

template <bool F32A>
__global__ __launch_bounds__(256) void k_gemm_mfma(const void* __restrict__ Aptr,
                                                   const unsigned short* __restrict__ Bt,
                                                   const float* __restrict__ bias,
                                                   const float* __restrict__ att,
                                                   unsigned short* __restrict__ H,
                                                   float* __restrict__ sdst,
                                                   float* __restrict__ ssrc, int M) {
  __shared__ float spi[2][128];
  __shared__ float spj[2][128];
  int tid = threadIdx.x;
  int w = tid >> 6, l = tid & 63;
  int g = l >> 4, li = l & 15;
  int row0 = blockIdx.x * 128;
  int mw = (w >> 1) * 64, nw = (w & 1) * 64;

  floatx4 acc[4][4] = {};   // [ti = row tile][tj = col tile]

  for (int ks = 0; ks < 4; ++ks) {
    short8 fa[4], fb[4];
#pragma unroll
    for (int t = 0; t < 4; ++t) {
      int row = row0 + mw + t * 16 + li;
      row = row < M ? row : M - 1;
      if (F32A) {
        const float* ap = (const float*)Aptr + (size_t)row * 128 + ks * 32 + g * 8;
        float4 v0 = *(const float4*)ap;
        float4 v1 = *(const float4*)(ap + 4);
        short8 f;
        f[0] = (short)f2bf(v0.x); f[1] = (short)f2bf(v0.y);
        f[2] = (short)f2bf(v0.z); f[3] = (short)f2bf(v0.w);
        f[4] = (short)f2bf(v1.x); f[5] = (short)f2bf(v1.y);
        f[6] = (short)f2bf(v1.z); f[7] = (short)f2bf(v1.w);
        fa[t] = f;
      } else {
        fa[t] = *(const short8*)((const unsigned short*)Aptr +
                                 (size_t)row * 128 + ks * 32 + g * 8);
      }
      fb[t] = *(const short8*)(Bt + (nw + t * 16 + li) * 128 + ks * 32 + g * 8);
    }
#pragma unroll
    for (int ti = 0; ti < 4; ++ti)
#pragma unroll
      for (int tj = 0; tj < 4; ++tj)
        acc[ti][tj] = __builtin_amdgcn_mfma_f32_16x16x32_bf16(fb[tj], fa[ti],
                                                              acc[ti][tj], 0, 0, 0);
  }

  float pis[4] = {0.f, 0.f, 0.f, 0.f};
  float pjs[4] = {0.f, 0.f, 0.f, 0.f};
#pragma unroll
  for (int tj = 0; tj < 4; ++tj) {
    int c0 = nw + tj * 16 + g * 4;
    float4 bb = *(const float4*)&bias[c0];
    float4 ai = *(const float4*)&att[c0];
    float4 aj = *(const float4*)&att[128 + c0];
#pragma unroll
    for (int ti = 0; ti < 4; ++ti) {
      int row = row0 + mw + ti * 16 + li;
      float v0 = acc[ti][tj][0] + bb.x;
      float v1 = acc[ti][tj][1] + bb.y;
      float v2 = acc[ti][tj][2] + bb.z;
      float v3 = acc[ti][tj][3] + bb.w;
      if (row < M) {
        ushort4 p;
        p.x = f2bf(v0); p.y = f2bf(v1); p.z = f2bf(v2); p.w = f2bf(v3);
        *(ushort4*)&H[(size_t)row * 128 + c0] = p;
      }
      pis[ti] += v0 * ai.x + v1 * ai.y + v2 * ai.z + v3 * ai.w;
      pjs[ti] += v0 * aj.x + v1 * aj.y + v2 * aj.z + v3 * aj.w;
    }
  }
#pragma unroll
  for (int ti = 0; ti < 4; ++ti) {
    float a = pis[ti], b = pjs[ti];
    a += __shfl_xor(a, 16); a += __shfl_xor(a, 32);
    b += __shfl_xor(b, 16); b += __shfl_xor(b, 32);
    if (g == 0) {
      spi[w & 1][mw + ti * 16 + li] = a;
      spj[w & 1][mw + ti * 16 + li] = b;
    }
  }
  __syncthreads();
  if (tid < 128) {
    int row = row0 + tid;
    if (row < M) {
      sdst[row] = spi[0][tid] + spi[1][tid];
      ssrc[row] = spj[0][tid] + spj[1][tid];
    }
  }
}

// ---------------- softmax + aggregation: 4 nodes/wave, batched-8 MLP ----------------
// offs holds END offsets (start of node n = offs[n-1], or 0). Output bf16.

__global__ __launch_bounds__(256) void k_gather(const unsigned short* __restrict__ H,
                                                const float* __restrict__ sdst,
                                                const float* __restrict__ ssrc,
                                                const int* __restrict__ csr,
                                                const int* __restrict__ offs,
                                                const float* __restrict__ bias,
                                                unsigned short* __restrict__ xout, int N) {
  int tid = threadIdx.x;
  int lane = tid & 63;
  int l16 = tid & 15;
  int gbase = lane & 48;         // group's base lane within the wave
  int n = blockIdx.x * 16 + (tid >> 4);
  bool valid = (n < N);
  int end = valid ? offs[n] : 0;
  int start = (valid && n > 0) ? offs[n - 1] : 0;
  float sdn = valid ? sdst[n] : 0.f;

  float m = -INFINITY, ssum = 0.f;
  float acc[8] = {};

  for (int base = start; base < end; base += 16) {
    int k = base + l16;
    int s = 0;
    float sc = -INFINITY;
    if (k < end) {
      s = csr[k];
      float e = sdn + ssrc[s];
      sc = e > 0.f ? e : 0.2f * e;
    }
    float cm = sc;
#pragma unroll
    for (int off = 8; off; off >>= 1) cm = fmaxf(cm, __shfl_xor(cm, off));
    float nm = fmaxf(m, cm);
    float scale = __expf(m - nm);      // first chunk: exp(-inf)=0, acc/ssum are 0
#pragma unroll
    for (int i = 0; i < 8; ++i) acc[i] *= scale;
    float wgt = (k < end) ? __expf(sc - nm) : 0.f;
    float cs = wgt;
#pragma unroll
    for (int off = 8; off; off >>= 1) cs += __shfl_xor(cs, off);
    ssum = ssum * scale + cs;
    m = nm;
    int cc = end - base; if (cc > 16) cc = 16;

    // batched accumulate: broadcast 8, issue 8 predicated loads, then FMA
    for (int jb = 0; jb < cc; jb += 8) {
      int bcnt = cc - jb; if (bcnt > 8) bcnt = 8;
      float wj[8];
      short8 hv[8];
#pragma unroll
      for (int j = 0; j < 8; ++j) {
        wj[j] = __shfl(wgt, gbase + jb + j);
        int sj = __shfl(s, gbase + jb + j);
        if (j < bcnt) hv[j] = *(const short8*)(H + (size_t)sj * 128 + l16 * 8);
      }
#pragma unroll
      for (int j = 0; j < 8; ++j) {
        if (j < bcnt) {
#pragma unroll
          for (int i = 0; i < 8; ++i)
            acc[i] += wj[j] * bf2f((unsigned short)hv[j][i]);
        }
      }
    }
  }

  if (valid) {
    float inv = 1.0f / (ssum + 1e-16f);
    float4 b0 = *(const float4*)&bias[l16 * 8];
    float4 b1 = *(const float4*)&bias[l16 * 8 + 4];
    float bb[8] = {b0.x, b0.y, b0.z, b0.w, b1.x, b1.y, b1.z, b1.w};
    short8 o;
#pragma unroll
    for (int i = 0; i < 8; ++i)
      o[i] = (short)f2bf(fmaxf(acc[i] * inv + bb[i], 0.f));
    *(short8*)(xout + (size_t)n * 128 + l16 * 8) = o;
  }
}

// ---------------- head: out = log_softmax(xb @ Wc + bc), swapped MFMA ----------------

__global__ __launch_bounds__(256) void k_head_mfma(const unsigned short* __restrict__ Xb,
                                                   const unsigned short* __restrict__ Wct,
                                                   const float* __restrict__ bc,
                                                   float* __restrict__ out, int M) {
  int tid = threadIdx.x;
  int w = tid >> 6, l = tid & 63;
  int g = l >> 4, li = l & 15;
  int row0 = blockIdx.x * 128;
  int mw = w * 32;

  floatx4 acc[2][4] = {};

  for (int ks = 0; ks < 4; ++ks) {
    short8 fa[2], fb[4];
#pragma unroll
    for (int t = 0; t < 2; ++t) {
      int row = row0 + mw + t * 16 + li;
      row = row < M ? row : M - 1;
      fa[t] = *(const short8*)(Xb + (size_t)row * 128 + ks * 32 + g * 8);
    }
#pragma unroll
    for (int t = 0; t < 4; ++t)
      fb[t] = *(const short8*)(Wct + (t * 16 + li) * 128 + ks * 32 + g * 8);
#pragma unroll
    for (int ti = 0; ti < 2; ++ti)
#pragma unroll
      for (int tj = 0; tj < 4; ++tj)
        acc[ti][tj] = __builtin_amdgcn_mfma_f32_16x16x32_bf16(fb[tj], fa[ti],
                                                              acc[ti][tj], 0, 0, 0);
  }

#pragma unroll
  for (int ti = 0; ti < 2; ++ti) {
    float v[16];
    float mx = -INFINITY;
#pragma unroll
    for (int tj = 0; tj < 4; ++tj) {
      int c0 = tj * 16 + g * 4;
      float4 bb = *(const float4*)&bc[c0];
      v[tj * 4 + 0] = acc[ti][tj][0] + bb.x;
      v[tj * 4 + 1] = acc[ti][tj][1] + bb.y;
      v[tj * 4 + 2] = acc[ti][tj][2] + bb.z;
      v[tj * 4 + 3] = acc[ti][tj][3] + bb.w;
#pragma unroll
      for (int q = 0; q < 4; ++q) mx = fmaxf(mx, v[tj * 4 + q]);
    }
    mx = fmaxf(mx, __shfl_xor(mx, 16));
    mx = fmaxf(mx, __shfl_xor(mx, 32));
    float s = 0.f;
#pragma unroll
    for (int q = 0; q < 16; ++q) s += __expf(v[q] - mx);
    s += __shfl_xor(s, 16);
    s += __shfl_xor(s, 32);
    float ls = mx + __logf(s);
    int row = row0 + mw + ti * 16 + li;
    if (row < M) {
#pragma unroll
      for (int tj = 0; tj < 4; ++tj) {
        float4 o = make_float4(v[tj * 4 + 0] - ls, v[tj * 4 + 1] - ls,
                               v[tj * 4 + 2] - ls, v[tj * 4 + 3] - ls);
        *(float4*)&out[(size_t)row * 64 + tj * 16 + g * 4] = o;
      }
    }
  }
}

// ---------------- launch ----------------

extern "C" void kernel_launch(void* const* d_in, const int* in_sizes, int n_in,
                              void* d_out, int out_size, void* d_ws, size_t ws_size,
                              hipStream_t stream) {
  const float* x      = (const float*)d_in[0];
  const int*   ei     = (const int*)d_in[1];
  const float* Ws     = (const float*)d_in[2];
  const float* bs     = (const float*)d_in[3];
  const float* atts   = (const float*)d_in[4];
  const float* biases = (const float*)d_in[5];
  const float* Wp1    = (const float*)d_in[6];
  const float* bp1    = (const float*)d_in[7];
  const float* Wp2    = (const float*)d_in[8];
  const float* bp2    = (const float*)d_in[9];
  float* out = (float*)d_out;

  int N = in_sizes[0] / 128;
  int E = in_sizes[1] / 2;
  int Np = (N + 3) & ~3;
  int nb = (N + 1023) / 1024;
  int histB = (E + 255) / 256;

  float* sdst = (float*)d_ws;
  float* ssrc = sdst + Np;
  float* bc   = ssrc + Np;
  unsigned short* xbuf = (unsigned short*)(bc + 64);   // bf16 gather output
  unsigned short* H    = xbuf + (size_t)Np * 128;      // bf16 h
  unsigned short* Wt   = H + (size_t)Np * 128;         // 3 x [n][k]
  unsigned short* Wct  = Wt + 3 * 16384;               // [64][128]
  int* deg    = (int*)(Wct + 8192);
  int* offs   = deg + Np;
  int* partial  = offs + Np;
  int* partialx = partial + 1024;
  int* csr      = partialx + 1028;

  // deg zero, then fused histogram + weight prep
  hipMemsetAsync(deg, 0, (size_t)N * sizeof(int), stream);
  k_hist_prep<<<histB + 224, 256, 0, stream>>>(ei, deg, E, Ws, Wp1, bp1, Wp2, bp2,
                                               Wt, Wct, bc, histB);
  k_scan1<<<nb, 1024, 0, stream>>>(deg, offs, partial, N);
  k_scan<<<1, 1024, 0, stream>>>(partial, partialx, nb);
  k_add<<<nb, 1024, 0, stream>>>(offs, partialx, N);
  k_fill<<<histB, 256, 0, stream>>>(ei, offs, csr, E);   // offs -> ends

  for (int l = 0; l < 3; ++l) {
    if (l == 0)
      k_gemm_mfma<true><<<(N + 127) / 128, 256, 0, stream>>>(
          x, Wt, bs, atts, H, sdst, ssrc, N);
    else
      k_gemm_mfma<false><<<(N + 127) / 128, 256, 0, stream>>>(
          xbuf, Wt + (size_t)l * 16384, bs + (size_t)l * 128,
          atts + (size_t)l * 256, H, sdst, ssrc, N);
    k_gather<<<(N + 15) / 16, 256, 0, stream>>>(H, sdst, ssrc, csr, offs,
                                                biases + (size_t)l * 128, xbuf, N);
  }

  k_head_mfma<<<(N + 127) / 128, 256, 0, stream>>>(xbuf, Wct, bc, out, N);
}